// Round 1
// baseline (30341.055 us; speedup 1.0000x reference)
//
#include <hip/hip_runtime.h>
#include <math.h>

#define BSZ 512
#define NV 30
#define NT 24
#define KM 750
#define SS 768   // state row stride in floats (x: cols 0..249, m: cols 250..749)

// ---------------- zero ----------------
__global__ void zero_kernel(float* p, int n) {
    int i = blockIdx.x * blockDim.x + threadIdx.x;
    int st = gridDim.x * blockDim.x;
    for (; i < n; i += st) p[i] = 0.f;
}

// ---------------- fused gate ----------------
// grid = (12, 8): blockIdx.x < 8 -> "mem" sector (N=500, computes z_sw AND z_mem),
//                 blockIdx.x >= 8 -> "sv" sector (N=250, computes z_sv).
// Each block: 64x64 output tile, 256 threads, 4x4 per thread, BK=16.
__launch_bounds__(256)
__global__ void gate_kernel(const float* __restrict__ Sin, float* __restrict__ Sout,
                            const float* __restrict__ Wsw, const float* __restrict__ bsw,
                            const float* __restrict__ Wmem, const float* __restrict__ bmem,
                            const float* __restrict__ Wsv, const float* __restrict__ bsv,
                            const int* __restrict__ letters, int t)
{
    const int tid = threadIdx.x;
    const int tx = tid & 15, ty = tid >> 4;
    const int m0 = blockIdx.y * 64;
    const bool memsec = (blockIdx.x < 8);
    const int n0 = (memsec ? blockIdx.x : (blockIdx.x - 8)) * 64;
    const int N = memsec ? 500 : 250;
    const float* __restrict__ W0 = memsec ? Wsw : Wsv;

    __shared__ float As[16][68];
    __shared__ float B0[16][68];
    __shared__ float B1[16][68];

    float acc0[4][4] = {{0.f}};
    float acc1[4][4] = {{0.f}};

    for (int k0 = 0; k0 < KM; k0 += 16) {
        // A tile: As[kk][row]
        {
            const int kk = tid & 15, r = tid >> 4;
            const bool ok = (k0 + kk) < KM;
            const float* src = Sin + (size_t)(m0 + r) * SS + k0 + kk;
            As[kk][r +  0] = ok ? src[ 0 * SS] : 0.f;
            As[kk][r + 16] = ok ? src[16 * SS] : 0.f;
            As[kk][r + 32] = ok ? src[32 * SS] : 0.f;
            As[kk][r + 48] = ok ? src[48 * SS] : 0.f;
        }
        // B tiles: B[kk][col]
        {
            const int c = tid & 63, kg = tid >> 6;
            #pragma unroll
            for (int i = 0; i < 4; i++) {
                const int kk = kg * 4 + i;
                const bool ok = ((k0 + kk) < KM) && ((n0 + c) < N);
                B0[kk][c] = ok ? W0[(size_t)(k0 + kk) * N + n0 + c] : 0.f;
                if (memsec)
                    B1[kk][c] = ok ? Wmem[(size_t)(k0 + kk) * 500 + n0 + c] : 0.f;
            }
        }
        __syncthreads();
        #pragma unroll
        for (int kk = 0; kk < 16; kk++) {
            float a[4], b0v[4], b1v[4];
            *(float4*)a   = *(const float4*)&As[kk][ty * 4];
            *(float4*)b0v = *(const float4*)&B0[kk][tx * 4];
            if (memsec) *(float4*)b1v = *(const float4*)&B1[kk][tx * 4];
            #pragma unroll
            for (int i = 0; i < 4; i++) {
                #pragma unroll
                for (int j = 0; j < 4; j++) {
                    acc0[i][j] = fmaf(a[i], b0v[j], acc0[i][j]);
                    if (memsec) acc1[i][j] = fmaf(a[i], b1v[j], acc1[i][j]);
                }
            }
        }
        __syncthreads();
    }

    // layer-1 one-hot contribution: add row (750 + letter) of each weight matrix
    if (letters != nullptr) {
        #pragma unroll
        for (int i = 0; i < 4; i++) {
            const int b = m0 + ty * 4 + i;
            const int lt = letters[b * NT + t];
            const float* r0 = W0 + (size_t)(KM + lt) * N;
            const float* r1 = Wmem + (size_t)(KM + lt) * 500;
            #pragma unroll
            for (int j = 0; j < 4; j++) {
                const int n = n0 + tx * 4 + j;
                if (n < N) {
                    acc0[i][j] += r0[n];
                    if (memsec) acc1[i][j] += r1[n];
                }
            }
        }
    }

    // epilogue
    if (memsec) {
        #pragma unroll
        for (int i = 0; i < 4; i++) {
            const int b = m0 + ty * 4 + i;
            #pragma unroll
            for (int j = 0; j < 4; j++) {
                const int n = n0 + tx * 4 + j;
                if (n < 500) {
                    const float s = 1.f / (1.f + expf(-(acc0[i][j] + bsw[n])));
                    const float mo = Sin[(size_t)b * SS + 250 + n];
                    Sout[(size_t)b * SS + 250 + n] =
                        mo * s + tanhf(acc1[i][j] + bmem[n]) * (1.f - s);
                }
            }
        }
    } else {
        #pragma unroll
        for (int i = 0; i < 4; i++) {
            const int b = m0 + ty * 4 + i;
            #pragma unroll
            for (int j = 0; j < 4; j++) {
                const int n = n0 + tx * 4 + j;
                if (n < 250)
                    Sout[(size_t)b * SS + n] = tanhf(acc0[i][j] + bsv[n]);
            }
        }
    }
}

// ---------------- head MLP layer: Y = tanh(X @ W + b) ----------------
__launch_bounds__(256)
__global__ void mlp_kernel(const float* __restrict__ X, int ldx, int K,
                           const float* __restrict__ W, const float* __restrict__ bias,
                           float* __restrict__ Y, int N)
{
    const int tid = threadIdx.x;
    const int tx = tid & 15, ty = tid >> 4;
    const int m0 = blockIdx.y * 64;
    const int n0 = blockIdx.x * 64;

    __shared__ float As[16][68];
    __shared__ float B0[16][68];

    float acc[4][4] = {{0.f}};

    for (int k0 = 0; k0 < K; k0 += 16) {
        {
            const int kk = tid & 15, r = tid >> 4;
            const bool ok = (k0 + kk) < K;
            const float* src = X + (size_t)(m0 + r) * ldx + k0 + kk;
            As[kk][r +  0] = ok ? src[ 0 * ldx] : 0.f;
            As[kk][r + 16] = ok ? src[16 * ldx] : 0.f;
            As[kk][r + 32] = ok ? src[32 * ldx] : 0.f;
            As[kk][r + 48] = ok ? src[48 * ldx] : 0.f;
        }
        {
            const int c = tid & 63, kg = tid >> 6;
            #pragma unroll
            for (int i = 0; i < 4; i++) {
                const int kk = kg * 4 + i;
                const bool ok = ((k0 + kk) < K) && ((n0 + c) < N);
                B0[kk][c] = ok ? W[(size_t)(k0 + kk) * N + n0 + c] : 0.f;
            }
        }
        __syncthreads();
        #pragma unroll
        for (int kk = 0; kk < 16; kk++) {
            float a[4], bv[4];
            *(float4*)a  = *(const float4*)&As[kk][ty * 4];
            *(float4*)bv = *(const float4*)&B0[kk][tx * 4];
            #pragma unroll
            for (int i = 0; i < 4; i++)
                #pragma unroll
                for (int j = 0; j < 4; j++)
                    acc[i][j] = fmaf(a[i], bv[j], acc[i][j]);
        }
        __syncthreads();
    }

    #pragma unroll
    for (int i = 0; i < 4; i++) {
        const int b = m0 + ty * 4 + i;
        #pragma unroll
        for (int j = 0; j < 4; j++) {
            const int n = n0 + tx * 4 + j;
            if (n < N)
                Y[(size_t)b * N + n] = tanhf(acc[i][j] + bias[n]);
        }
    }
}

// ---------------- final: logits (K=100, N=30) + softmax ----------------
__global__ void head_final(const float* __restrict__ Y4, const float* __restrict__ W,
                           const float* __restrict__ bias, float* __restrict__ out)
{
    const int row = blockIdx.x;
    __shared__ float y[100];
    __shared__ float z[NV];
    for (int k = threadIdx.x; k < 100; k += 64) y[k] = Y4[row * 100 + k];
    __syncthreads();
    const int n = threadIdx.x;
    if (n < NV) {
        float acc = bias[n];
        for (int k = 0; k < 100; k++) acc = fmaf(y[k], W[k * NV + n], acc);
        z[n] = acc;
    }
    __syncthreads();
    if (n < NV) {
        float mx = -1e30f;
        for (int i = 0; i < NV; i++) mx = fmaxf(mx, z[i]);
        float sum = 0.f;
        for (int i = 0; i < NV; i++) sum += expf(z[i] - mx);
        out[row * NV + n] = expf(z[n] - mx) / sum;
    }
}

extern "C" void kernel_launch(void* const* d_in, const int* in_sizes, int n_in,
                              void* d_out, int out_size, void* d_ws, size_t ws_size,
                              hipStream_t stream)
{
    const int*   letters = (const int*)  d_in[0];
    const float* w1_sv   = (const float*)d_in[1];
    const float* b1_sv   = (const float*)d_in[2];
    const float* w1_mem  = (const float*)d_in[3];
    const float* b1_mem  = (const float*)d_in[4];
    const float* w1_sw   = (const float*)d_in[5];
    const float* b1_sw   = (const float*)d_in[6];
    const float* w_sv    = (const float*)d_in[7];
    const float* b_sv    = (const float*)d_in[8];
    const float* w_mem   = (const float*)d_in[9];
    const float* b_mem   = (const float*)d_in[10];
    const float* w_sw    = (const float*)d_in[11];
    const float* b_sw    = (const float*)d_in[12];
    const float* wp1 = (const float*)d_in[13]; const float* bp1 = (const float*)d_in[14];
    const float* wp2 = (const float*)d_in[15]; const float* bp2 = (const float*)d_in[16];
    const float* wp3 = (const float*)d_in[17]; const float* bp3 = (const float*)d_in[18];
    const float* wp4 = (const float*)d_in[19]; const float* bp4 = (const float*)d_in[20];
    const float* wp5 = (const float*)d_in[21]; const float* bp5 = (const float*)d_in[22];

    float* S0 = (float*)d_ws;
    float* S1 = S0 + (size_t)BSZ * SS;
    float* Y1 = S1 + (size_t)BSZ * SS;
    float* Y2 = Y1 + (size_t)BSZ * 450;
    float* Y3 = Y2 + (size_t)BSZ * 300;
    float* Y4 = Y3 + (size_t)BSZ * 200;

    zero_kernel<<<512, 256, 0, stream>>>(S0, BSZ * SS);

    float* cur = S0;
    float* nxt = S1;
    const dim3 ggrid(12, 8);
    for (int t = 0; t < NT; t++) {
        // layer 1 (sees one-hot via letter-row add)
        gate_kernel<<<ggrid, 256, 0, stream>>>(cur, nxt,
            w1_sw, b1_sw, w1_mem, b1_mem, w1_sv, b1_sv, letters, t);
        { float* tmp = cur; cur = nxt; nxt = tmp; }
        // layers 2..6
        for (int l = 0; l < 5; l++) {
            gate_kernel<<<ggrid, 256, 0, stream>>>(cur, nxt,
                w_sw  + (size_t)l * KM * 500, b_sw  + (size_t)l * 500,
                w_mem + (size_t)l * KM * 500, b_mem + (size_t)l * 500,
                w_sv  + (size_t)l * KM * 250, b_sv  + (size_t)l * 250,
                nullptr, 0);
            { float* tmp = cur; cur = nxt; nxt = tmp; }
        }
    }

    // head
    mlp_kernel<<<dim3(8, 8), 256, 0, stream>>>(cur, SS, 750, wp1, bp1, Y1, 450);
    mlp_kernel<<<dim3(5, 8), 256, 0, stream>>>(Y1, 450, 450, wp2, bp2, Y2, 300);
    mlp_kernel<<<dim3(4, 8), 256, 0, stream>>>(Y2, 300, 300, wp3, bp3, Y3, 200);
    mlp_kernel<<<dim3(2, 8), 256, 0, stream>>>(Y3, 200, 200, wp4, bp4, Y4, 100);
    head_final<<<512, 64, 0, stream>>>(Y4, wp5, bp5, (float*)d_out);
}

// Round 2
// 9264.905 us; speedup vs baseline: 3.2748x; 3.2748x over previous
//
#include <hip/hip_runtime.h>
#include <math.h>

#define BSZ 512
#define NV 30
#define NT 24
#define KM 750
#define SS 768    // state row stride (x: cols 0..249, m: cols 250..749)
#define ZLD 1280  // z buffer row stride (sw: 0..499, mem: 500..999, sv: 1000..1249)

// ---------------- zero ----------------
__global__ void zero_kernel(float* p, int n) {
    int i = blockIdx.x * blockDim.x + threadIdx.x;
    int st = gridDim.x * blockDim.x;
    for (; i < n; i += st) p[i] = 0.f;
}

// ---------------- gate GEMM: z = Sin[:, :750] @ [Wsw|Wmem|Wsv], K-split x2 ----------------
// grid (20, 16, 2), 128 threads. 32x64 tile / block, 4x4 per thread, BK=32 double-buffered.
__launch_bounds__(128)
__global__ void gate_gemm(const float* __restrict__ Sin,
                          const float* __restrict__ Wsw,
                          const float* __restrict__ Wmem,
                          const float* __restrict__ Wsv,
                          float* __restrict__ zbuf)
{
    const int tid  = threadIdx.x;
    const int tile = blockIdx.x;
    const int m0   = blockIdx.y * 32;
    const int kbeg = blockIdx.z * 375;
    const int kend = kbeg + 375;

    const float* __restrict__ W; int N, n0, zoff;
    if (tile < 8)       { W = Wsw;  N = 500; n0 = tile * 64;        zoff = 0;    }
    else if (tile < 16) { W = Wmem; N = 500; n0 = (tile - 8) * 64;  zoff = 500;  }
    else                { W = Wsv;  N = 250; n0 = (tile - 16) * 64; zoff = 1000; }

    float* __restrict__ zout = zbuf + (size_t)blockIdx.z * BSZ * ZLD;

    __shared__ float As[2][32][36];   // [k][row], pad 36 keeps float4 reads 16B-aligned
    __shared__ float Bs[2][32][68];   // [k][col]

    const int tx = tid & 15, ty = tid >> 4;     // compute: cols tx*4.., rows ty*4..
    const int kl = tid & 31, rl = tid >> 5;     // A load: k=kl, rows rl+4i
    const int cl = tid & 63, kg = tid >> 6;     // B load: col cl, k=kg+2i
    const bool cok = (n0 + cl) < N;

    float acc[4][4] = {{0.f}};
    float ar[8], br[16];

    // prologue: stage kt=0 (375 > 32, no k guard needed)
    {
        const float* a = Sin + (size_t)(m0 + rl) * SS + kbeg + kl;
        #pragma unroll
        for (int i = 0; i < 8; i++) ar[i] = a[(size_t)(4 * i) * SS];
        #pragma unroll
        for (int i = 0; i < 16; i++)
            br[i] = cok ? W[(size_t)(kbeg + kg + 2 * i) * N + n0 + cl] : 0.f;
        #pragma unroll
        for (int i = 0; i < 8; i++) As[0][kl][rl + 4 * i] = ar[i];
        #pragma unroll
        for (int i = 0; i < 16; i++) Bs[0][kg + 2 * i][cl] = br[i];
    }
    __syncthreads();

    int buf = 0;
    const int NK = 12;  // ceil(375/32)
    #pragma unroll 1
    for (int kt = 0; kt < NK; kt++) {
        const bool more = (kt + 1 < NK);
        if (more) {
            const int k0 = kbeg + (kt + 1) * 32;
            const bool ka = (k0 + kl) < kend;
            const float* a = Sin + (size_t)(m0 + rl) * SS + k0 + kl;
            #pragma unroll
            for (int i = 0; i < 8; i++) ar[i] = ka ? a[(size_t)(4 * i) * SS] : 0.f;
            #pragma unroll
            for (int i = 0; i < 16; i++) {
                const int kk = k0 + kg + 2 * i;
                br[i] = (cok && kk < kend) ? W[(size_t)kk * N + n0 + cl] : 0.f;
            }
        }
        #pragma unroll
        for (int kk = 0; kk < 32; kk++) {
            float4 av = *(const float4*)&As[buf][kk][ty * 4];
            float4 bv = *(const float4*)&Bs[buf][kk][tx * 4];
            const float aa[4] = {av.x, av.y, av.z, av.w};
            const float bb[4] = {bv.x, bv.y, bv.z, bv.w};
            #pragma unroll
            for (int i = 0; i < 4; i++)
                #pragma unroll
                for (int j = 0; j < 4; j++)
                    acc[i][j] = fmaf(aa[i], bb[j], acc[i][j]);
        }
        if (more) {
            #pragma unroll
            for (int i = 0; i < 8; i++) As[buf ^ 1][kl][rl + 4 * i] = ar[i];
            #pragma unroll
            for (int i = 0; i < 16; i++) Bs[buf ^ 1][kg + 2 * i][cl] = br[i];
            __syncthreads();
            buf ^= 1;
        }
    }

    #pragma unroll
    for (int i = 0; i < 4; i++) {
        const int b = m0 + ty * 4 + i;
        float* zr = zout + (size_t)b * ZLD + zoff + n0 + tx * 4;
        #pragma unroll
        for (int j = 0; j < 4; j++)
            if (n0 + tx * 4 + j < N) zr[j] = acc[i][j];
    }
}

// ---------------- gate epilogue: sum K-partials, bias, one-hot row, gating ----------------
// grid (3, 512), 256 threads
__global__ void gate_epi(const float* __restrict__ zbuf, const float* __restrict__ Sin,
                         float* __restrict__ Sout,
                         const float* __restrict__ bsw, const float* __restrict__ bmem,
                         const float* __restrict__ bsv,
                         const float* __restrict__ Wsw, const float* __restrict__ Wmem,
                         const float* __restrict__ Wsv,
                         const int* __restrict__ letters, int t)
{
    const int b = blockIdx.y;
    const int n = blockIdx.x * 256 + threadIdx.x;
    if (n >= 750) return;
    const float* z0 = zbuf + (size_t)b * ZLD;
    const float* z1 = z0 + (size_t)BSZ * ZLD;
    const int lt = letters ? letters[b * NT + t] : -1;
    if (n < 250) {
        float z = z0[1000 + n] + z1[1000 + n] + bsv[n];
        if (lt >= 0) z += Wsv[(size_t)(KM + lt) * 250 + n];
        Sout[(size_t)b * SS + n] = tanhf(z);
    } else {
        const int j = n - 250;
        float zs = z0[j] + z1[j] + bsw[j];
        float zm = z0[500 + j] + z1[500 + j] + bmem[j];
        if (lt >= 0) {
            zs += Wsw[(size_t)(KM + lt) * 500 + j];
            zm += Wmem[(size_t)(KM + lt) * 500 + j];
        }
        const float s = 1.f / (1.f + expf(-zs));
        const float mo = Sin[(size_t)b * SS + 250 + j];
        Sout[(size_t)b * SS + 250 + j] = mo * s + tanhf(zm) * (1.f - s);
    }
}

// ---------------- head GEMM: Y = tanh(X @ W + b), same tile structure ----------------
__launch_bounds__(128)
__global__ void head_gemm(const float* __restrict__ X, int ldx, int K,
                          const float* __restrict__ W, const float* __restrict__ bias,
                          float* __restrict__ Y, int N)
{
    const int tid = threadIdx.x;
    const int m0 = blockIdx.y * 32;
    const int n0 = blockIdx.x * 64;

    __shared__ float As[2][32][36];
    __shared__ float Bs[2][32][68];

    const int tx = tid & 15, ty = tid >> 4;
    const int kl = tid & 31, rl = tid >> 5;
    const int cl = tid & 63, kg = tid >> 6;
    const bool cok = (n0 + cl) < N;

    float acc[4][4] = {{0.f}};
    float ar[8], br[16];

    {
        const float* a = X + (size_t)(m0 + rl) * ldx + kl;
        #pragma unroll
        for (int i = 0; i < 8; i++) ar[i] = a[(size_t)(4 * i) * ldx];
        #pragma unroll
        for (int i = 0; i < 16; i++)
            br[i] = cok ? W[(size_t)(kg + 2 * i) * N + n0 + cl] : 0.f;
        #pragma unroll
        for (int i = 0; i < 8; i++) As[0][kl][rl + 4 * i] = ar[i];
        #pragma unroll
        for (int i = 0; i < 16; i++) Bs[0][kg + 2 * i][cl] = br[i];
    }
    __syncthreads();

    int buf = 0;
    const int NK = (K + 31) / 32;
    #pragma unroll 1
    for (int kt = 0; kt < NK; kt++) {
        const bool more = (kt + 1 < NK);
        if (more) {
            const int k0 = (kt + 1) * 32;
            const bool ka = (k0 + kl) < K;
            const float* a = X + (size_t)(m0 + rl) * ldx + k0 + kl;
            #pragma unroll
            for (int i = 0; i < 8; i++) ar[i] = ka ? a[(size_t)(4 * i) * ldx] : 0.f;
            #pragma unroll
            for (int i = 0; i < 16; i++) {
                const int kk = k0 + kg + 2 * i;
                br[i] = (cok && kk < K) ? W[(size_t)kk * N + n0 + cl] : 0.f;
            }
        }
        #pragma unroll
        for (int kk = 0; kk < 32; kk++) {
            float4 av = *(const float4*)&As[buf][kk][ty * 4];
            float4 bv = *(const float4*)&Bs[buf][kk][tx * 4];
            const float aa[4] = {av.x, av.y, av.z, av.w};
            const float bb[4] = {bv.x, bv.y, bv.z, bv.w};
            #pragma unroll
            for (int i = 0; i < 4; i++)
                #pragma unroll
                for (int j = 0; j < 4; j++)
                    acc[i][j] = fmaf(aa[i], bb[j], acc[i][j]);
        }
        if (more) {
            #pragma unroll
            for (int i = 0; i < 8; i++) As[buf ^ 1][kl][rl + 4 * i] = ar[i];
            #pragma unroll
            for (int i = 0; i < 16; i++) Bs[buf ^ 1][kg + 2 * i][cl] = br[i];
            __syncthreads();
            buf ^= 1;
        }
    }

    #pragma unroll
    for (int i = 0; i < 4; i++) {
        const int b = m0 + ty * 4 + i;
        #pragma unroll
        for (int j = 0; j < 4; j++) {
            const int n = n0 + tx * 4 + j;
            if (n < N) Y[(size_t)b * N + n] = tanhf(acc[i][j] + bias[n]);
        }
    }
}

// ---------------- final: logits (K=100, N=30) + softmax ----------------
__global__ void head_final(const float* __restrict__ Y4, const float* __restrict__ W,
                           const float* __restrict__ bias, float* __restrict__ out)
{
    const int row = blockIdx.x;
    __shared__ float y[100];
    __shared__ float z[NV];
    for (int k = threadIdx.x; k < 100; k += 64) y[k] = Y4[row * 100 + k];
    __syncthreads();
    const int n = threadIdx.x;
    if (n < NV) {
        float acc = bias[n];
        for (int k = 0; k < 100; k++) acc = fmaf(y[k], W[k * NV + n], acc);
        z[n] = acc;
    }
    __syncthreads();
    if (n < NV) {
        float mx = -1e30f;
        for (int i = 0; i < NV; i++) mx = fmaxf(mx, z[i]);
        float sum = 0.f;
        for (int i = 0; i < NV; i++) sum += expf(z[i] - mx);
        out[row * NV + n] = expf(z[n] - mx) / sum;
    }
}

extern "C" void kernel_launch(void* const* d_in, const int* in_sizes, int n_in,
                              void* d_out, int out_size, void* d_ws, size_t ws_size,
                              hipStream_t stream)
{
    const int*   letters = (const int*)  d_in[0];
    const float* w1_sv   = (const float*)d_in[1];
    const float* b1_sv   = (const float*)d_in[2];
    const float* w1_mem  = (const float*)d_in[3];
    const float* b1_mem  = (const float*)d_in[4];
    const float* w1_sw   = (const float*)d_in[5];
    const float* b1_sw   = (const float*)d_in[6];
    const float* w_sv    = (const float*)d_in[7];
    const float* b_sv    = (const float*)d_in[8];
    const float* w_mem   = (const float*)d_in[9];
    const float* b_mem   = (const float*)d_in[10];
    const float* w_sw    = (const float*)d_in[11];
    const float* b_sw    = (const float*)d_in[12];
    const float* wp1 = (const float*)d_in[13]; const float* bp1 = (const float*)d_in[14];
    const float* wp2 = (const float*)d_in[15]; const float* bp2 = (const float*)d_in[16];
    const float* wp3 = (const float*)d_in[17]; const float* bp3 = (const float*)d_in[18];
    const float* wp4 = (const float*)d_in[19]; const float* bp4 = (const float*)d_in[20];
    const float* wp5 = (const float*)d_in[21]; const float* bp5 = (const float*)d_in[22];

    float* S0 = (float*)d_ws;
    float* S1 = S0 + (size_t)BSZ * SS;
    float* Zb = S1 + (size_t)BSZ * SS;                 // 2 * 512 * ZLD
    float* Y1 = Zb + 2 * (size_t)BSZ * ZLD;
    float* Y2 = Y1 + (size_t)BSZ * 450;
    float* Y3 = Y2 + (size_t)BSZ * 300;
    float* Y4 = Y3 + (size_t)BSZ * 200;

    zero_kernel<<<512, 256, 0, stream>>>(S0, BSZ * SS);

    float* cur = S0;
    float* nxt = S1;
    const dim3 ggrid(20, 16, 2);
    const dim3 egrid(3, BSZ);
    for (int t = 0; t < NT; t++) {
        gate_gemm<<<ggrid, 128, 0, stream>>>(cur, w1_sw, w1_mem, w1_sv, Zb);
        gate_epi<<<egrid, 256, 0, stream>>>(Zb, cur, nxt, b1_sw, b1_mem, b1_sv,
                                            w1_sw, w1_mem, w1_sv, letters, t);
        { float* tmp = cur; cur = nxt; nxt = tmp; }
        for (int l = 0; l < 5; l++) {
            gate_gemm<<<ggrid, 128, 0, stream>>>(cur,
                w_sw  + (size_t)l * KM * 500,
                w_mem + (size_t)l * KM * 500,
                w_sv  + (size_t)l * KM * 250, Zb);
            gate_epi<<<egrid, 256, 0, stream>>>(Zb, cur, nxt,
                b_sw + (size_t)l * 500, b_mem + (size_t)l * 500, b_sv + (size_t)l * 250,
                nullptr, nullptr, nullptr, nullptr, 0);
            { float* tmp = cur; cur = nxt; nxt = tmp; }
        }
    }

    head_gemm<<<dim3(8, 16), 128, 0, stream>>>(cur, SS, 750, wp1, bp1, Y1, 450);
    head_gemm<<<dim3(5, 16), 128, 0, stream>>>(Y1, 450, 450, wp2, bp2, Y2, 300);
    head_gemm<<<dim3(4, 16), 128, 0, stream>>>(Y2, 300, 300, wp3, bp3, Y3, 200);
    head_gemm<<<dim3(2, 16), 128, 0, stream>>>(Y3, 200, 200, wp4, bp4, Y4, 100);
    head_final<<<BSZ, 64, 0, stream>>>(Y4, wp5, bp5, (float*)d_out);
}

// Round 3
// 6977.522 us; speedup vs baseline: 4.3484x; 1.3278x over previous
//
#include <hip/hip_runtime.h>
#include <math.h>

#define BSZ 512
#define NV 30
#define NT 24
#define KM 750
#define SS 768    // state row stride (x: cols 0..249, m: cols 250..749)
#define ZLD 1280  // z buffer row stride (sw: 0..499, mem: 500..999, sv: 1000..1249)
#define KSPLIT 3
#define KPER 250  // K per split

// ---------------- zero ----------------
__global__ void zero_kernel(float* p, int n) {
    int i = blockIdx.x * blockDim.x + threadIdx.x;
    int st = gridDim.x * blockDim.x;
    for (; i < n; i += st) p[i] = 0.f;
}

// ---------------- gate GEMM: z = Sin[:, :750] @ [Wsw|Wmem|Wsv], K-split x3 ----------------
// grid (20, 16, 3), 128 threads. 32x64 tile / block, 4x4 per thread, BK=32 double-buffered.
__launch_bounds__(128)
__global__ void gate_gemm(const float* __restrict__ Sin,
                          const float* __restrict__ Wsw,
                          const float* __restrict__ Wmem,
                          const float* __restrict__ Wsv,
                          float* __restrict__ zbuf)
{
    const int tid  = threadIdx.x;
    const int tile = blockIdx.x;
    const int m0   = blockIdx.y * 32;
    const int kbeg = blockIdx.z * KPER;
    const int kend = kbeg + KPER;

    const float* __restrict__ W; int N, n0, zoff;
    if (tile < 8)       { W = Wsw;  N = 500; n0 = tile * 64;        zoff = 0;    }
    else if (tile < 16) { W = Wmem; N = 500; n0 = (tile - 8) * 64;  zoff = 500;  }
    else                { W = Wsv;  N = 250; n0 = (tile - 16) * 64; zoff = 1000; }

    float* __restrict__ zout = zbuf + (size_t)blockIdx.z * BSZ * ZLD;

    __shared__ float As[2][32][36];   // [k][row]
    __shared__ float Bs[2][32][68];   // [k][col]

    const int tx = tid & 15, ty = tid >> 4;     // compute: cols tx*4.., rows ty*4..
    const int kl = tid & 31, rl = tid >> 5;     // A load: k=kl, rows rl+4i
    const int cl = tid & 63, kg = tid >> 6;     // B load: col cl, k=kg+2i
    const bool cok = (n0 + cl) < N;

    float acc[4][4] = {{0.f}};
    float ar[8], br[16];

    // prologue: stage kt=0 (KPER=250 > 32, no k guard needed)
    {
        const float* a = Sin + (size_t)(m0 + rl) * SS + kbeg + kl;
        #pragma unroll
        for (int i = 0; i < 8; i++) ar[i] = a[(size_t)(4 * i) * SS];
        #pragma unroll
        for (int i = 0; i < 16; i++)
            br[i] = cok ? W[(size_t)(kbeg + kg + 2 * i) * N + n0 + cl] : 0.f;
        #pragma unroll
        for (int i = 0; i < 8; i++) As[0][kl][rl + 4 * i] = ar[i];
        #pragma unroll
        for (int i = 0; i < 16; i++) Bs[0][kg + 2 * i][cl] = br[i];
    }
    __syncthreads();

    int buf = 0;
    const int NK = (KPER + 31) / 32;  // 8
    #pragma unroll 1
    for (int kt = 0; kt < NK; kt++) {
        const bool more = (kt + 1 < NK);
        if (more) {
            const int k0 = kbeg + (kt + 1) * 32;
            const bool ka = (k0 + kl) < kend;
            const float* a = Sin + (size_t)(m0 + rl) * SS + k0 + kl;
            #pragma unroll
            for (int i = 0; i < 8; i++) ar[i] = ka ? a[(size_t)(4 * i) * SS] : 0.f;
            #pragma unroll
            for (int i = 0; i < 16; i++) {
                const int kk = k0 + kg + 2 * i;
                br[i] = (cok && kk < kend) ? W[(size_t)kk * N + n0 + cl] : 0.f;
            }
        }
        #pragma unroll
        for (int kk = 0; kk < 32; kk++) {
            float4 av = *(const float4*)&As[buf][kk][ty * 4];
            float4 bv = *(const float4*)&Bs[buf][kk][tx * 4];
            const float aa[4] = {av.x, av.y, av.z, av.w};
            const float bb[4] = {bv.x, bv.y, bv.z, bv.w};
            #pragma unroll
            for (int i = 0; i < 4; i++)
                #pragma unroll
                for (int j = 0; j < 4; j++)
                    acc[i][j] = fmaf(aa[i], bb[j], acc[i][j]);
        }
        if (more) {
            #pragma unroll
            for (int i = 0; i < 8; i++) As[buf ^ 1][kl][rl + 4 * i] = ar[i];
            #pragma unroll
            for (int i = 0; i < 16; i++) Bs[buf ^ 1][kg + 2 * i][cl] = br[i];
            __syncthreads();
            buf ^= 1;
        }
    }

    #pragma unroll
    for (int i = 0; i < 4; i++) {
        const int b = m0 + ty * 4 + i;
        float* zr = zout + (size_t)b * ZLD + zoff + n0 + tx * 4;
        #pragma unroll
        for (int j = 0; j < 4; j++)
            if (n0 + tx * 4 + j < N) zr[j] = acc[i][j];
    }
}

// ---------------- gate epilogue: sum 3 K-partials, bias, one-hot row, gating ----------------
// grid (3, 512), 256 threads
__global__ void gate_epi(const float* __restrict__ zbuf, const float* __restrict__ Sin,
                         float* __restrict__ Sout,
                         const float* __restrict__ bsw, const float* __restrict__ bmem,
                         const float* __restrict__ bsv,
                         const float* __restrict__ Wsw, const float* __restrict__ Wmem,
                         const float* __restrict__ Wsv,
                         const int* __restrict__ letters, int t)
{
    const int b = blockIdx.y;
    const int n = blockIdx.x * 256 + threadIdx.x;
    if (n >= 750) return;
    const float* z0 = zbuf + (size_t)b * ZLD;
    const float* z1 = z0 + (size_t)BSZ * ZLD;
    const float* z2 = z1 + (size_t)BSZ * ZLD;
    const int lt = letters ? letters[b * NT + t] : -1;
    if (n < 250) {
        float z = z0[1000 + n] + z1[1000 + n] + z2[1000 + n] + bsv[n];
        if (lt >= 0) z += Wsv[(size_t)(KM + lt) * 250 + n];
        Sout[(size_t)b * SS + n] = tanhf(z);
    } else {
        const int j = n - 250;
        float zs = z0[j] + z1[j] + z2[j] + bsw[j];
        float zm = z0[500 + j] + z1[500 + j] + z2[500 + j] + bmem[j];
        if (lt >= 0) {
            zs += Wsw[(size_t)(KM + lt) * 500 + j];
            zm += Wmem[(size_t)(KM + lt) * 500 + j];
        }
        const float s = 1.f / (1.f + expf(-zs));
        const float mo = Sin[(size_t)b * SS + 250 + j];
        Sout[(size_t)b * SS + 250 + j] = mo * s + tanhf(zm) * (1.f - s);
    }
}

// ---------------- head GEMM: Y = tanh(X @ W + b) ----------------
__launch_bounds__(128)
__global__ void head_gemm(const float* __restrict__ X, int ldx, int K,
                          const float* __restrict__ W, const float* __restrict__ bias,
                          float* __restrict__ Y, int N)
{
    const int tid = threadIdx.x;
    const int m0 = blockIdx.y * 32;
    const int n0 = blockIdx.x * 64;

    __shared__ float As[2][32][36];
    __shared__ float Bs[2][32][68];

    const int tx = tid & 15, ty = tid >> 4;
    const int kl = tid & 31, rl = tid >> 5;
    const int cl = tid & 63, kg = tid >> 6;
    const bool cok = (n0 + cl) < N;

    float acc[4][4] = {{0.f}};
    float ar[8], br[16];

    {
        const float* a = X + (size_t)(m0 + rl) * ldx + kl;
        #pragma unroll
        for (int i = 0; i < 8; i++) ar[i] = a[(size_t)(4 * i) * ldx];
        #pragma unroll
        for (int i = 0; i < 16; i++)
            br[i] = cok ? W[(size_t)(kg + 2 * i) * N + n0 + cl] : 0.f;
        #pragma unroll
        for (int i = 0; i < 8; i++) As[0][kl][rl + 4 * i] = ar[i];
        #pragma unroll
        for (int i = 0; i < 16; i++) Bs[0][kg + 2 * i][cl] = br[i];
    }
    __syncthreads();

    int buf = 0;
    const int NK = (K + 31) / 32;
    #pragma unroll 1
    for (int kt = 0; kt < NK; kt++) {
        const bool more = (kt + 1 < NK);
        if (more) {
            const int k0 = (kt + 1) * 32;
            const bool ka = (k0 + kl) < K;
            const float* a = X + (size_t)(m0 + rl) * ldx + k0 + kl;
            #pragma unroll
            for (int i = 0; i < 8; i++) ar[i] = ka ? a[(size_t)(4 * i) * ldx] : 0.f;
            #pragma unroll
            for (int i = 0; i < 16; i++) {
                const int kk = k0 + kg + 2 * i;
                br[i] = (cok && kk < K) ? W[(size_t)kk * N + n0 + cl] : 0.f;
            }
        }
        #pragma unroll
        for (int kk = 0; kk < 32; kk++) {
            float4 av = *(const float4*)&As[buf][kk][ty * 4];
            float4 bv = *(const float4*)&Bs[buf][kk][tx * 4];
            const float aa[4] = {av.x, av.y, av.z, av.w};
            const float bb[4] = {bv.x, bv.y, bv.z, bv.w};
            #pragma unroll
            for (int i = 0; i < 4; i++)
                #pragma unroll
                for (int j = 0; j < 4; j++)
                    acc[i][j] = fmaf(aa[i], bb[j], acc[i][j]);
        }
        if (more) {
            #pragma unroll
            for (int i = 0; i < 8; i++) As[buf ^ 1][kl][rl + 4 * i] = ar[i];
            #pragma unroll
            for (int i = 0; i < 16; i++) Bs[buf ^ 1][kg + 2 * i][cl] = br[i];
            __syncthreads();
            buf ^= 1;
        }
    }

    #pragma unroll
    for (int i = 0; i < 4; i++) {
        const int b = m0 + ty * 4 + i;
        #pragma unroll
        for (int j = 0; j < 4; j++) {
            const int n = n0 + tx * 4 + j;
            if (n < N) Y[(size_t)b * N + n] = tanhf(acc[i][j] + bias[n]);
        }
    }
}

// ---------------- final: logits (K=100, N=30) + softmax ----------------
__global__ void head_final(const float* __restrict__ Y4, const float* __restrict__ W,
                           const float* __restrict__ bias, float* __restrict__ out)
{
    const int row = blockIdx.x;
    __shared__ float y[100];
    __shared__ float z[NV];
    for (int k = threadIdx.x; k < 100; k += 64) y[k] = Y4[row * 100 + k];
    __syncthreads();
    const int n = threadIdx.x;
    if (n < NV) {
        float acc = bias[n];
        for (int k = 0; k < 100; k++) acc = fmaf(y[k], W[k * NV + n], acc);
        z[n] = acc;
    }
    __syncthreads();
    if (n < NV) {
        float mx = -1e30f;
        for (int i = 0; i < NV; i++) mx = fmaxf(mx, z[i]);
        float sum = 0.f;
        for (int i = 0; i < NV; i++) sum += expf(z[i] - mx);
        out[row * NV + n] = expf(z[n] - mx) / sum;
    }
}

extern "C" void kernel_launch(void* const* d_in, const int* in_sizes, int n_in,
                              void* d_out, int out_size, void* d_ws, size_t ws_size,
                              hipStream_t stream)
{
    const int*   letters = (const int*)  d_in[0];
    const float* w1_sv   = (const float*)d_in[1];
    const float* b1_sv   = (const float*)d_in[2];
    const float* w1_mem  = (const float*)d_in[3];
    const float* b1_mem  = (const float*)d_in[4];
    const float* w1_sw   = (const float*)d_in[5];
    const float* b1_sw   = (const float*)d_in[6];
    const float* w_sv    = (const float*)d_in[7];
    const float* b_sv    = (const float*)d_in[8];
    const float* w_mem   = (const float*)d_in[9];
    const float* b_mem   = (const float*)d_in[10];
    const float* w_sw    = (const float*)d_in[11];
    const float* b_sw    = (const float*)d_in[12];
    const float* wp1 = (const float*)d_in[13]; const float* bp1 = (const float*)d_in[14];
    const float* wp2 = (const float*)d_in[15]; const float* bp2 = (const float*)d_in[16];
    const float* wp3 = (const float*)d_in[17]; const float* bp3 = (const float*)d_in[18];
    const float* wp4 = (const float*)d_in[19]; const float* bp4 = (const float*)d_in[20];
    const float* wp5 = (const float*)d_in[21]; const float* bp5 = (const float*)d_in[22];

    float* S0 = (float*)d_ws;
    float* S1 = S0 + (size_t)BSZ * SS;
    float* Zb = S1 + (size_t)BSZ * SS;                 // KSPLIT * 512 * ZLD floats
    // head buffers alias the z region (recurrence is done before head runs)
    float* Y1 = Zb;
    float* Y2 = Y1 + (size_t)BSZ * 450;
    float* Y3 = Y2 + (size_t)BSZ * 300;
    float* Y4 = Y3 + (size_t)BSZ * 200;

    zero_kernel<<<512, 256, 0, stream>>>(S0, BSZ * SS);

    float* cur = S0;
    float* nxt = S1;
    const dim3 ggrid(20, 16, KSPLIT);
    const dim3 egrid(3, BSZ);
    for (int t = 0; t < NT; t++) {
        gate_gemm<<<ggrid, 128, 0, stream>>>(cur, w1_sw, w1_mem, w1_sv, Zb);
        gate_epi<<<egrid, 256, 0, stream>>>(Zb, cur, nxt, b1_sw, b1_mem, b1_sv,
                                            w1_sw, w1_mem, w1_sv, letters, t);
        { float* tmp = cur; cur = nxt; nxt = tmp; }
        for (int l = 0; l < 5; l++) {
            gate_gemm<<<ggrid, 128, 0, stream>>>(cur,
                w_sw  + (size_t)l * KM * 500,
                w_mem + (size_t)l * KM * 500,
                w_sv  + (size_t)l * KM * 250, Zb);
            gate_epi<<<egrid, 256, 0, stream>>>(Zb, cur, nxt,
                b_sw + (size_t)l * 500, b_mem + (size_t)l * 500, b_sv + (size_t)l * 250,
                nullptr, nullptr, nullptr, nullptr, 0);
            { float* tmp = cur; cur = nxt; nxt = tmp; }
        }
    }

    head_gemm<<<dim3(8, 16), 128, 0, stream>>>(cur, SS, 750, wp1, bp1, Y1, 450);
    head_gemm<<<dim3(5, 16), 128, 0, stream>>>(Y1, 450, 450, wp2, bp2, Y2, 300);
    head_gemm<<<dim3(4, 16), 128, 0, stream>>>(Y2, 300, 300, wp3, bp3, Y3, 200);
    head_gemm<<<dim3(2, 16), 128, 0, stream>>>(Y3, 200, 200, wp4, bp4, Y4, 100);
    head_final<<<BSZ, 64, 0, stream>>>(Y4, wp5, bp5, (float*)d_out);
}